// Round 8
// baseline (121.449 us; speedup 1.0000x reference)
//
#include <hip/hip_runtime.h>

#define SS 102
#define QSCALE 0.72134752044448170368f  // 0.5 * log2(e)

typedef __fp16 h2 __attribute__((ext_vector_type(2)));
typedef __fp16 h4 __attribute__((ext_vector_type(4)));
typedef __fp16 h8 __attribute__((ext_vector_type(8)));

__device__ __forceinline__ void store4h(__fp16* p, float a, float b,
                                        float c, float d) {
    h2 lo = __builtin_amdgcn_cvt_pkrtz(a, b);
    h2 hi = __builtin_amdgcn_cvt_pkrtz(c, d);
    *(h4*)p = __builtin_shufflevector(lo, hi, 0, 1, 2, 3);
}

// One WAVE processes one batch end-to-end; waves own disjoint LDS regions,
// so the kernel contains NO __syncthreads at all (intra-wave lgkmcnt only).
// Per-wave LDS region, 9792 B:
//   RAWH 0..4896    f16 [3][102][8] staged raw q/k/v
//        (aliased by COMB f32 [102][8] = 3264 B once RAW is dead)
//   QH   4896..6528 f16 [2][102][4] rotated+prescaled q
//   KV   6528..9792 f16 [2][102][8] per key: K d0..3 | V d0..3
__global__ __launch_bounds__(256, 4) void mha_fused_kernel(
    const float* __restrict__ query, const float* __restrict__ key,
    const float* __restrict__ value, const float* __restrict__ wq,
    const float* __restrict__ wk, const float* __restrict__ wvp,
    const float* __restrict__ wo, float* __restrict__ out)
{
    __shared__ __align__(16) unsigned char lds[4 * 9792];
    const int t = threadIdx.x;
    const int w = t >> 6, lane = t & 63;
    unsigned char* base = lds + w * 9792;
    __fp16* RAWH = (__fp16*)base;
    __fp16* QH   = (__fp16*)(base + 4896);
    __fp16* KV   = (__fp16*)(base + 6528);
    float*  COMB = (float*)base;          // alias of RAWH (RAW dead by then)

    const size_t b = (size_t)blockIdx.x * 4 + w;

    // ---- stage this wave's batch: 204 float4 per tensor, coalesced ----
    const float4* q4 = (const float4*)(query + b * 816);
    const float4* k4 = (const float4*)(key   + b * 816);
    const float4* v4 = (const float4*)(value + b * 816);
    float4 rq[4], rk[4], rv[4];
#pragma unroll
    for (int c = 0; c < 4; ++c) {
        const int i = lane + 64 * c;
        if (i < 204) { rq[c] = q4[i]; rk[c] = k4[i]; rv[c] = v4[i]; }
    }
#pragma unroll
    for (int c = 0; c < 4; ++c) {
        const int i = lane + 64 * c;
        if (i < 204) {
            store4h(RAWH + i * 4,        rq[c].x, rq[c].y, rq[c].z, rq[c].w);
            store4h(RAWH + 816 + i * 4,  rk[c].x, rk[c].y, rk[c].z, rk[c].w);
            store4h(RAWH + 1632 + i * 4, rv[c].x, rv[c].y, rv[c].z, rv[c].w);
        }
    }

    // ---- projections (weights wave-uniform -> SGPRs) + fused rotary ----
    // reference broadcast quirk: head0 *= sin(s), head1 *= cos(s);
    // pair: out_even=(x0-x1)*w, out_odd=(x1+x0)*w; q folds 0.5*log2(e).
    float snv[2], csv[2];
#pragma unroll
    for (int c = 0; c < 2; ++c) {
        const int r = lane + 64 * c;
        snv[c] = __sinf((float)r);
        csv[c] = __cosf((float)r);
    }
#pragma unroll
    for (int T = 0; T < 3; ++T) {
        const float* W = (T == 0) ? wq : (T == 1) ? wk : wvp;
#pragma unroll
        for (int c = 0; c < 2; ++c) {
            const int r = lane + 64 * c;
            if (r < SS) {
                const h8 raw = *(const h8*)(RAWH + T * 816 + r * 8);
                float x[8];
#pragma unroll
                for (int ch = 0; ch < 8; ++ch) {
                    float acc = 0.f;
#pragma unroll
                    for (int j = 0; j < 8; ++j)
                        acc += (float)raw[j] * W[ch * 8 + j];
                    x[ch] = acc;
                }
                if (T == 2) {             // v -> back half of KV records
                    store4h(KV + (0 * SS + r) * 8 + 4, x[0], x[1], x[2], x[3]);
                    store4h(KV + (1 * SS + r) * 8 + 4, x[4], x[5], x[6], x[7]);
                } else {                  // q/k -> rotary then QH / KV front
#pragma unroll
                    for (int h = 0; h < 2; ++h) {
                        float wr = h ? csv[c] : snv[c];
                        if (T == 0) wr *= QSCALE;
                        const float y0 = (x[4*h+0] - x[4*h+1]) * wr;
                        const float y1 = (x[4*h+1] + x[4*h+0]) * wr;
                        const float y2 = (x[4*h+2] - x[4*h+3]) * wr;
                        const float y3 = (x[4*h+3] + x[4*h+2]) * wr;
                        if (T == 0) store4h(QH + (h * SS + r) * 4, y0, y1, y2, y3);
                        else        store4h(KV + (h * SS + r) * 8, y0, y1, y2, y3);
                    }
                }
            }
        }
    }

    // ---- attention: half-wave per head; each lane owns 4 rows of its head,
    // so ONE broadcast ds_read_b128 per key serves all rows (conflict-free).
    {
        const int h   = lane >> 5;
        const int idx = lane & 31;
        h2 qlo[4], qhi[4];
        int rows[4]; bool ract[4];
#pragma unroll
        for (int c = 0; c < 4; ++c) {
            int r = idx + 32 * c;
            ract[c] = (r < SS);
            if (!ract[c]) r = 0;          // duplicate row 0, result discarded
            rows[c] = r;
            const h4 q = *(const h4*)(QH + (h * SS + r) * 4);
            qlo[c] = __builtin_shufflevector(q, q, 0, 1);
            qhi[c] = __builtin_shufflevector(q, q, 2, 3);
        }
        float a0[4] = {}, a1[4] = {}, a2[4] = {}, a3[4] = {}, L[4] = {};
        const __fp16* KVh = KV + h * SS * 8;
#pragma unroll 2
        for (int k = 0; k < SS; ++k) {
            const h8 rec = *(const h8*)(KVh + k * 8);
            const h2 k01 = {rec[0], rec[1]};
            const h2 k23 = {rec[2], rec[3]};
            const float v0 = (float)rec[4], v1 = (float)rec[5];
            const float v2 = (float)rec[6], v3 = (float)rec[7];
#pragma unroll
            for (int c = 0; c < 4; ++c) {
                const float s = __builtin_amdgcn_fdot2(
                    k01, qlo[c],
                    __builtin_amdgcn_fdot2(k23, qhi[c], 0.f, false), false);
                const float p = __builtin_amdgcn_exp2f(s);
                L[c] += p;
                a0[c] += p * v0; a1[c] += p * v1;
                a2[c] += p * v2; a3[c] += p * v3;
            }
        }
#pragma unroll
        for (int c = 0; c < 4; ++c) {
            if (ract[c]) {
                const float inv = 1.f / L[c];
                *(float4*)(COMB + rows[c] * 8 + h * 4) =
                    (float4){a0[c] * inv, a1[c] * inv, a2[c] * inv, a3[c] * inv};
            }
        }
    }

    // ---- output projection (wo in SGPRs) + vectorized store ----
#pragma unroll
    for (int c = 0; c < 2; ++c) {
        const int r = lane + 64 * c;
        if (r < SS) {
            const float4 a = *(const float4*)(COMB + r * 8);
            const float4 d = *(const float4*)(COMB + r * 8 + 4);
            float x[8];
#pragma unroll
            for (int ch = 0; ch < 8; ++ch) {
                x[ch] = a.x * wo[ch * 8 + 0] + a.y * wo[ch * 8 + 1]
                      + a.z * wo[ch * 8 + 2] + a.w * wo[ch * 8 + 3]
                      + d.x * wo[ch * 8 + 4] + d.y * wo[ch * 8 + 5]
                      + d.z * wo[ch * 8 + 6] + d.w * wo[ch * 8 + 7];
            }
            float* o = out + b * 816 + r * 8;
            *(float4*)(o)     = (float4){x[0], x[1], x[2], x[3]};
            *(float4*)(o + 4) = (float4){x[4], x[5], x[6], x[7]};
        }
    }
}

extern "C" void kernel_launch(void* const* d_in, const int* in_sizes, int n_in,
                              void* d_out, int out_size, void* d_ws, size_t ws_size,
                              hipStream_t stream) {
    const float* query = (const float*)d_in[0];
    const float* key   = (const float*)d_in[1];
    const float* value = (const float*)d_in[2];
    const float* wq    = (const float*)d_in[3];
    const float* wk    = (const float*)d_in[4];
    const float* wv    = (const float*)d_in[5];
    const float* wo    = (const float*)d_in[6];
    float* out = (float*)d_out;
    mha_fused_kernel<<<1024, 256, 0, stream>>>(query, key, value, wq, wk, wv, wo, out);
}